// Round 4
// baseline (1497.264 us; speedup 1.0000x reference)
//
#include <hip/hip_runtime.h>

typedef float f32x2 __attribute__((ext_vector_type(2)));
typedef float f32x4 __attribute__((ext_vector_type(4)));

#define BB 256
#define TT 1024
#define HH 128
#define CC 2

// tanh(u) = 1 - 2/(exp(2u)+1); saturates gracefully to +/-1, no branches.
__device__ __forceinline__ float ftanh(float u) {
    float e = __expf(2.0f * u);
    float r = __builtin_amdgcn_rcpf(e + 1.0f);
    return fmaf(-2.0f, r, 1.0f);
}

__global__ __launch_bounds__(64, 1) void rnn_kernel(
    const float* __restrict__ x, const float* __restrict__ W_ih,
    const float* __restrict__ W_hh, const float* __restrict__ b_ih,
    const float* __restrict__ b_hh, const float* __restrict__ W_fc,
    const float* __restrict__ b_fc, float* __restrict__ out)
{
    const int b = blockIdx.x;
    const int l = threadIdx.x;          // 0..63, single wave
    const int r0 = l, r1 = l + 64;      // the two rows this lane owns

    __shared__ float xs[TT];            // input sequence
    __shared__ float hs[2][HH];         // hidden state, double-buffered

    // preload x row (coalesced f32x4; single wave -> no barrier needed,
    // same-wave LDS ops are in-order)
    {
        const f32x4* xr = (const f32x4*)(x + (size_t)b * TT);
        f32x4* xd = (f32x4*)xs;
        #pragma unroll
        for (int i = 0; i < 4; ++i) xd[l + 64 * i] = xr[l + 64 * i];
    }

    // per-lane constants
    const float wih0 = W_ih[r0], wih1 = W_ih[r1];
    const float bias0 = b_ih[r0] + b_hh[r0];
    const float bias1 = b_ih[r1] + b_hh[r1];
    const float wf00 = W_fc[r0],      wf01 = W_fc[r1];       // class 0
    const float wf10 = W_fc[HH + r0], wf11 = W_fc[HH + r1];  // class 1
    const float bf0 = b_fc[0], bf1 = b_fc[1];

    // both W_hh rows in registers: 2 x 128 floats = 256 VGPRs
    f32x4 w0[32], w1[32];
    {
        const f32x4* p0 = (const f32x4*)(W_hh + (size_t)r0 * HH);
        const f32x4* p1 = (const f32x4*)(W_hh + (size_t)r1 * HH);
        #pragma unroll
        for (int j = 0; j < 32; ++j) { w0[j] = p0[j]; w1[j] = p1[j]; }
    }

    float hn0 = 0.f, hn1 = 0.f;         // h_0 = 0
    float* o = out + (size_t)b * TT * CC;

    // Iteration T: publishes h_T (regs) to LDS, emits logits of h_T (stored
    // as out[T-1] for T>0 during iteration T+0's latency window... i.e. here),
    // then computes h_{T+1}. Single wave => no barriers anywhere.
#define STEP(BUF, T)                                                         \
    {                                                                        \
        hs[BUF][l]      = hn0;  /* stride-1 b32 writes: conflict-free */     \
        hs[BUF][l + 64] = hn1;                                               \
        const float xt = xs[(T)];       /* broadcast read */                 \
        /* logits of h_T from registers; fills the LDS write->read window */ \
        float c0 = fmaf(wf00, hn0, wf01 * hn1);                              \
        float c1 = fmaf(wf10, hn0, wf11 * hn1);                              \
        c0 += __shfl_xor(c0, 1);  c1 += __shfl_xor(c1, 1);                   \
        c0 += __shfl_xor(c0, 2);  c1 += __shfl_xor(c1, 2);                   \
        c0 += __shfl_xor(c0, 4);  c1 += __shfl_xor(c1, 4);                   \
        c0 += __shfl_xor(c0, 8);  c1 += __shfl_xor(c1, 8);                   \
        c0 += __shfl_xor(c0, 16); c1 += __shfl_xor(c1, 16);                  \
        c0 += __shfl_xor(c0, 32); c1 += __shfl_xor(c1, 32);                  \
        if ((T) > 0 && l == 0) {                                             \
            f32x2 cc = { c0 + bf0, c1 + bf1 };                               \
            *(f32x2*)(o + ((T) - 1) * CC) = cc;                              \
        }                                                                    \
        /* matvec: broadcast b128 reads (all lanes same addr, 0 conflicts) */\
        f32x2 aE0 = {0.f, 0.f}, aO0 = {0.f, 0.f};                            \
        f32x2 aE1 = {0.f, 0.f}, aO1 = {0.f, 0.f};                            \
        const f32x4* hb = (const f32x4*)hs[BUF];                             \
        _Pragma("unroll")                                                    \
        for (int j = 0; j < 32; ++j) {                                       \
            f32x4 hv = hb[j];                                                \
            aE0 = __builtin_elementwise_fma(w0[j].xy, hv.xy, aE0);           \
            aO0 = __builtin_elementwise_fma(w0[j].zw, hv.zw, aO0);           \
            aE1 = __builtin_elementwise_fma(w1[j].xy, hv.xy, aE1);           \
            aO1 = __builtin_elementwise_fma(w1[j].zw, hv.zw, aO1);           \
        }                                                                    \
        float dot0 = (aE0.x + aE0.y) + (aO0.x + aO0.y);                      \
        float dot1 = (aE1.x + aE1.y) + (aO1.x + aO1.y);                      \
        hn0 = ftanh(fmaf(xt, wih0, bias0) + dot0);                           \
        hn1 = ftanh(fmaf(xt, wih1, bias1) + dot1);                           \
    }

    #pragma unroll 1
    for (int t = 0; t < TT; t += 2) {
        STEP(0, t)
        STEP(1, t + 1)
    }
#undef STEP

    // logits of the final hidden state h_TT -> out[TT-1]
    {
        float c0 = fmaf(wf00, hn0, wf01 * hn1);
        float c1 = fmaf(wf10, hn0, wf11 * hn1);
        c0 += __shfl_xor(c0, 1);  c1 += __shfl_xor(c1, 1);
        c0 += __shfl_xor(c0, 2);  c1 += __shfl_xor(c1, 2);
        c0 += __shfl_xor(c0, 4);  c1 += __shfl_xor(c1, 4);
        c0 += __shfl_xor(c0, 8);  c1 += __shfl_xor(c1, 8);
        c0 += __shfl_xor(c0, 16); c1 += __shfl_xor(c1, 16);
        c0 += __shfl_xor(c0, 32); c1 += __shfl_xor(c1, 32);
        if (l == 0) {
            f32x2 cc = { c0 + bf0, c1 + bf1 };
            *(f32x2*)(o + (TT - 1) * CC) = cc;
        }
    }
}

extern "C" void kernel_launch(void* const* d_in, const int* in_sizes, int n_in,
                              void* d_out, int out_size, void* d_ws, size_t ws_size,
                              hipStream_t stream) {
    const float* x    = (const float*)d_in[0];
    const float* W_ih = (const float*)d_in[1];
    const float* W_hh = (const float*)d_in[2];
    const float* b_ih = (const float*)d_in[3];
    const float* b_hh = (const float*)d_in[4];
    const float* W_fc = (const float*)d_in[5];
    const float* b_fc = (const float*)d_in[6];
    float* out = (float*)d_out;

    rnn_kernel<<<BB, 64, 0, stream>>>(x, W_ih, W_hh, b_ih, b_hh, W_fc, b_fc, out);
}

// Round 5
// 669.790 us; speedup vs baseline: 2.2354x; 2.2354x over previous
//
#include <hip/hip_runtime.h>

typedef float f32x2 __attribute__((ext_vector_type(2)));
typedef float f32x4 __attribute__((ext_vector_type(4)));

#define BB 256
#define TT 1024
#define HH 128
#define CC 2

// tanh(u) = 1 - 2/(exp(2u)+1); branchless, saturates to +/-1. Validated R3:
// absmax identical to ocml tanhf path (9.77e-4).
__device__ __forceinline__ float ftanh(float u) {
    float e = __expf(2.0f * u);
    float r = __builtin_amdgcn_rcpf(e + 1.0f);
    return fmaf(-2.0f, r, 1.0f);
}

__global__ __launch_bounds__(128, 1) void rnn_kernel(
    const float* __restrict__ x, const float* __restrict__ W_ih,
    const float* __restrict__ W_hh, const float* __restrict__ b_ih,
    const float* __restrict__ b_hh, const float* __restrict__ W_fc,
    const float* __restrict__ b_fc, float* __restrict__ out)
{
    const int b   = blockIdx.x;
    const int tid = threadIdx.x;     // 0..127
    const int l   = tid & 63;
    const int wv  = tid >> 6;        // 0..1
    const int r   = tid;             // this lane's output row

    __shared__ float xs[TT];         // input sequence
    __shared__ float hs[2][HH];      // hidden state, double-buffered
    __shared__ f32x2 qp[2][2];       // [buf][wave] logit partials (c0,c1)

    // preload x row (coalesced f32x4)
    {
        const f32x4* xr = (const f32x4*)(x + (size_t)b * TT);
        f32x4* xd = (f32x4*)xs;
        xd[tid]       = xr[tid];
        xd[tid + 128] = xr[tid + 128];
    }
    hs[0][tid] = 0.f;                // h_0 = 0

    // per-lane constants
    const float wih  = W_ih[r];                  // INPUT_DIM = 1
    const float bias = b_ih[r] + b_hh[r];
    const float wf0  = W_fc[r];                  // class 0 weight for this row
    const float wf1  = W_fc[HH + r];             // class 1
    const float bf0  = b_fc[0], bf1 = b_fc[1];

    // one W_hh row in registers: 128 fp32 = 128 VGPRs (fits: arch cap 256)
    f32x4 wr[32];
    {
        const f32x4* wrow = (const f32x4*)(W_hh + (size_t)r * HH);
        #pragma unroll
        for (int j = 0; j < 32; ++j) wr[j] = wrow[j];
    }

    float hn = 0.f;                  // this lane's h_t (register copy)
    float* o = out + (size_t)b * TT * CC;

    __syncthreads();                 // hs[0] + xs visible

    #pragma unroll 2
    for (int t = 0; t < TT; ++t) {
        const int cur = t & 1, nxt = cur ^ 1;

        // store out[t-2] = logits(h_{t-1}) from qp[nxt] (written iter t-1,
        // protected by the barrier at end of iter t-1). Off critical path.
        if (t >= 2 && tid == 0) {
            f32x2 s = qp[nxt][0] + qp[nxt][1];
            s.x += bf0; s.y += bf1;
            *(f32x2*)(o + (t - 2) * CC) = s;
        }

        // matvec: 32 broadcast b128 reads of h_t, 64 v_pk_fma_f32
        const f32x4* hb = (const f32x4*)hs[cur];
        f32x2 a0 = {0.f, 0.f}, a1 = {0.f, 0.f}, a2 = {0.f, 0.f}, a3 = {0.f, 0.f};
        #pragma unroll
        for (int j = 0; j < 32; j += 2) {
            f32x4 v0 = hb[j], v1 = hb[j + 1];
            a0 = __builtin_elementwise_fma(wr[j].xy,     v0.xy, a0);
            a1 = __builtin_elementwise_fma(wr[j].zw,     v0.zw, a1);
            a2 = __builtin_elementwise_fma(wr[j + 1].xy, v1.xy, a2);
            a3 = __builtin_elementwise_fma(wr[j + 1].zw, v1.zw, a3);
        }

        // logits partials of h_t from the register copy — these shuffles are
        // independent of the matvec and hide in its LDS-stall slots.
        float q0 = wf0 * hn, q1 = wf1 * hn;
        q0 += __shfl_xor(q0, 1);  q1 += __shfl_xor(q1, 1);
        q0 += __shfl_xor(q0, 2);  q1 += __shfl_xor(q1, 2);
        q0 += __shfl_xor(q0, 4);  q1 += __shfl_xor(q1, 4);
        q0 += __shfl_xor(q0, 8);  q1 += __shfl_xor(q1, 8);
        q0 += __shfl_xor(q0, 16); q1 += __shfl_xor(q1, 16);
        q0 += __shfl_xor(q0, 32); q1 += __shfl_xor(q1, 32);
        if (l == 0) { f32x2 qq = {q0, q1}; qp[cur][wv] = qq; }

        // finish the dot, tanh, publish h_{t+1}
        f32x2 aa = (a0 + a1) + (a2 + a3);
        float dot = aa.x + aa.y;
        hn = ftanh(fmaf(xs[t], wih, bias) + dot);
        hs[nxt][r] = hn;             // stride-1 b32, conflict-free

        __syncthreads();             // the single per-step barrier
    }

    // epilogue: out[TT-2] = logits(h_{TT-1}) from qp; out[TT-1] = logits(h_TT)
    if (tid == 0) {
        const int pb = (TT - 1) & 1;
        f32x2 s = qp[pb][0] + qp[pb][1];
        s.x += bf0; s.y += bf1;
        *(f32x2*)(o + (TT - 2) * CC) = s;
    }
    {
        float q0 = wf0 * hn, q1 = wf1 * hn;
        q0 += __shfl_xor(q0, 1);  q1 += __shfl_xor(q1, 1);
        q0 += __shfl_xor(q0, 2);  q1 += __shfl_xor(q1, 2);
        q0 += __shfl_xor(q0, 4);  q1 += __shfl_xor(q1, 4);
        q0 += __shfl_xor(q0, 8);  q1 += __shfl_xor(q1, 8);
        q0 += __shfl_xor(q0, 16); q1 += __shfl_xor(q1, 16);
        q0 += __shfl_xor(q0, 32); q1 += __shfl_xor(q1, 32);
        if (l == 0) { f32x2 qq = {q0, q1}; qp[0][wv] = qq; }
    }
    __syncthreads();
    if (tid == 0) {
        f32x2 s = qp[0][0] + qp[0][1];
        s.x += bf0; s.y += bf1;
        *(f32x2*)(o + (TT - 1) * CC) = s;
    }
}

extern "C" void kernel_launch(void* const* d_in, const int* in_sizes, int n_in,
                              void* d_out, int out_size, void* d_ws, size_t ws_size,
                              hipStream_t stream) {
    const float* x    = (const float*)d_in[0];
    const float* W_ih = (const float*)d_in[1];
    const float* W_hh = (const float*)d_in[2];
    const float* b_ih = (const float*)d_in[3];
    const float* b_hh = (const float*)d_in[4];
    const float* W_fc = (const float*)d_in[5];
    const float* b_fc = (const float*)d_in[6];
    float* out = (float*)d_out;

    rnn_kernel<<<BB, 128, 0, stream>>>(x, W_ih, W_hh, b_ih, b_hh, W_fc, b_fc, out);
}